// Round 9
// baseline (476.455 us; speedup 1.0000x reference)
//
#include <hip/hip_runtime.h>
#include <hip/hip_bf16.h>
#include <math.h>

#define NNODES 50000
#define NEDGES 800000
#define HNB 128                 // histogram blocks per row
#define HBINS 50176             // 196*256, >= NNODES
#define SCAN_NB 196             // HBINS/256

typedef short s8v __attribute__((ext_vector_type(8)));
typedef float f4v __attribute__((ext_vector_type(4)));
typedef unsigned int u32;
using bf16 = __hip_bfloat16;

static __device__ __forceinline__ float bflo(unsigned int x) {
    union { unsigned int i; float f; } c; c.i = x << 16; return c.f;
}
static __device__ __forceinline__ float bfhi(unsigned int x) {
    union { unsigned int i; float f; } c; c.i = x & 0xffff0000u; return c.f;
}
static __device__ __forceinline__ void fma8(float* a, float w, uint4 q) {
    a[0] += w * bflo(q.x); a[1] += w * bfhi(q.x);
    a[2] += w * bflo(q.y); a[3] += w * bfhi(q.y);
    a[4] += w * bflo(q.z); a[5] += w * bfhi(q.z);
    a[6] += w * bflo(q.w); a[7] += w * bfhi(q.w);
}
// async global->LDS, 16 B per lane; LDS dst = wave-uniform base + lane*16
static __device__ __forceinline__ void gld_lds16(const void* g, void* l) {
    __builtin_amdgcn_global_load_lds((const __attribute__((address_space(1))) u32*)g,
                                     (__attribute__((address_space(3))) u32*)l, 16, 0, 0);
}

// ---------------- weight prep ----------------
// stack+transpose [[W],[LW]] -> bf16 wt[256][512]
__global__ void k_packbt(const float* __restrict__ W, const float* __restrict__ LW,
                         bf16* __restrict__ out, int CC) {
    int i = blockIdx.x * blockDim.x + threadIdx.x;
    if (i >= CC * 512) return;
    int n = i / 512, k = i % 512;   // out[n][k] = stackedB[k][n]
    float v = (k < 256) ? W[k * CC + n] : LW[(k - 256) * CC + n];
    out[i] = __float2bfloat16(v);
}
// transpose single [256][128] -> bf16 [128][256]
__global__ void k_packt(const float* __restrict__ W, bf16* __restrict__ out) {
    int i = blockIdx.x * blockDim.x + threadIdx.x;
    if (i >= 128 * 256) return;
    int n = i / 256, k = i % 256;
    out[i] = __float2bfloat16(W[k * 128 + n]);
}

// ---------------- x fp32 -> bf16 into right half of ghcat[N,512] ----------------

__global__ void k_f2b_strided(const float* __restrict__ x, ushort* __restrict__ gh) {
    int i = blockIdx.x * blockDim.x + threadIdx.x;   // one per 4 elems
    if (i >= NNODES * 64) return;
    int v = i >> 6, c = (i & 63) * 4;
    float4 f = *(const float4*)(x + (size_t)v * 256 + c);
    union { bf16 h[4]; uint2 u; } o;
    o.h[0] = __float2bfloat16(f.x); o.h[1] = __float2bfloat16(f.y);
    o.h[2] = __float2bfloat16(f.z); o.h[3] = __float2bfloat16(f.w);
    *(uint2*)(gh + (size_t)v * 512 + 256 + c) = o.u;
}

// ---------------- degree histograms via LDS (no global atomics) ----------------

__global__ __launch_bounds__(256) void k_hist(const int* __restrict__ ei, ushort* __restrict__ partials) {
    __shared__ unsigned int h32[HBINS / 2];   // 100352 B LDS
    int b = blockIdx.x, row = blockIdx.y, t = threadIdx.x;
    for (int i = t; i < HBINS / 2; i += 256) h32[i] = 0;
    __syncthreads();
    const int chunk = NEDGES / HNB;  // 6250
    int beg = b * chunk, end = beg + chunk;
    const int* p = ei + (size_t)row * NEDGES;
    for (int e = beg + t; e < end; e += 256) {
        int id = p[e];
        atomicAdd(&h32[id >> 1], 1u << (16 * (id & 1)));
    }
    __syncthreads();
    unsigned int* o32 = (unsigned int*)(partials + ((size_t)row * HNB + b) * HBINS);
    for (int i = t; i < HBINS / 2; i += 256) o32[i] = h32[i];
}

// reduce partials: y=0 -> rsqrt_out table; y=1 -> in_cnt + per-256-node block_sums
__global__ __launch_bounds__(256) void k_hist_reduce(const ushort* __restrict__ partials,
                                                     float* __restrict__ rsqrt_out,
                                                     int* __restrict__ in_cnt,
                                                     int* __restrict__ block_sums) {
    __shared__ int sm[256];
    int row = blockIdx.y;
    int i = blockIdx.x * 256 + threadIdx.x;
    const ushort* p = partials + (size_t)row * HNB * HBINS + i;
    int s = 0;
#pragma unroll 4
    for (int b = 0; b < HNB; ++b) s += p[(size_t)b * HBINS];
    if (row == 0) {
        if (i < NNODES) rsqrt_out[i] = rsqrtf((float)s);
    } else {
        if (i < NNODES) in_cnt[i] = s;
        sm[threadIdx.x] = s;
        __syncthreads();
        for (int off = 128; off > 0; off >>= 1) {
            if (threadIdx.x < off) sm[threadIdx.x] += sm[threadIdx.x + off];
            __syncthreads();
        }
        if (threadIdx.x == 0) block_sums[blockIdx.x] = sm[0];
    }
}

// ---------------- scan ----------------

__global__ void k_scan_blocks(const int* __restrict__ block_sums, int* __restrict__ block_base, int nb) {
    __shared__ int s[256];
    int t = threadIdx.x;
    int v = (t < nb) ? block_sums[t] : 0;
    s[t] = v;
    __syncthreads();
    for (int off = 1; off < 256; off <<= 1) {
        int u = (t >= off) ? s[t - off] : 0;
        __syncthreads();
        s[t] += u;
        __syncthreads();
    }
    block_base[t] = s[t] - v;  // exclusive
}

__global__ void k_scan_final(const int* __restrict__ in_cnt, const int* __restrict__ block_base,
                             int* __restrict__ offsets, int* __restrict__ cursor) {
    __shared__ int s[256];
    int b = blockIdx.x, t = threadIdx.x;
    int i = b * 256 + t;
    int v = (i < NNODES) ? in_cnt[i] : 0;
    s[t] = v;
    __syncthreads();
    for (int off = 1; off < 256; off <<= 1) {
        int u = (t >= off) ? s[t - off] : 0;
        __syncthreads();
        s[t] += u;
        __syncthreads();
    }
    int excl = s[t] - v + block_base[b];
    if (i < NNODES) { offsets[i] = excl; cursor[i] = excl; }
    if (i == NNODES - 1) offsets[NNODES] = excl + v;
}

// counting-sort scatter: (src, out-norm) packed int2 per edge, bucketed by dst
__global__ void k_scatter(const int* __restrict__ ei, const float* __restrict__ rsqrt_out,
                          int* __restrict__ cursor, int2* __restrict__ edge_sw) {
    int e = blockIdx.x * blockDim.x + threadIdx.x;
    if (e < NEDGES) {
        int r = ei[e], c = ei[NEDGES + e];
        int p = atomicAdd(&cursor[c], 1);
        edge_sw[p] = make_int2(r, __float_as_int(rsqrt_out[r]));
    }
}

// ---------------- gather: G = in_norm * (S . src), column-split passes ----------------
// SST: source row stride (ushorts). OFP32: 0 -> bf16 out (stride 512, left half of gh),
// 1 -> fp32 out (stride 128). Pass y covers cols [y*64, y*64+64).
template<int SST, int OFP32>
__global__ __launch_bounds__(256) void k_gather(const ushort* __restrict__ hsrc,
                                                const int* __restrict__ offsets,
                                                const int2* __restrict__ edge_sw,
                                                void* __restrict__ Gdst) {
    int lane = threadIdx.x & 63;
    int v = blockIdx.x * 32 + (threadIdx.x >> 6) * 8 + (lane >> 3);
    if (v >= NNODES) return;
    int sl = lane & 7;
    int col0 = blockIdx.y * 64;

    int beg = offsets[v], end = offsets[v + 1];
    float a0[8], a1[8];
#pragma unroll
    for (int c = 0; c < 8; ++c) { a0[c] = 0.f; a1[c] = 0.f; }

    const ushort* base = hsrc + col0 + sl * 8;
    int j = beg;
    for (; j + 2 <= end; j += 2) {
        int2 e0 = edge_sw[j];
        int2 e1 = edge_sw[j + 1];
        uint4 q0 = *(const uint4*)(base + (size_t)e0.x * SST);
        uint4 q1 = *(const uint4*)(base + (size_t)e1.x * SST);
        fma8(a0, __int_as_float(e0.y), q0);
        fma8(a1, __int_as_float(e1.y), q1);
    }
    if (j < end) {
        int2 e0 = edge_sw[j];
        uint4 q0 = *(const uint4*)(base + (size_t)e0.x * SST);
        fma8(a0, __int_as_float(e0.y), q0);
    }
    float sc = (end > beg) ? rsqrtf((float)(end - beg)) : 0.f;
    if (OFP32) {
        float* op = (float*)Gdst + (size_t)v * 128 + col0 + sl * 8;
        *(float4*)op = (float4){(a0[0]+a1[0])*sc, (a0[1]+a1[1])*sc, (a0[2]+a1[2])*sc, (a0[3]+a1[3])*sc};
        *(float4*)(op+4) = (float4){(a0[4]+a1[4])*sc, (a0[5]+a1[5])*sc, (a0[6]+a1[6])*sc, (a0[7]+a1[7])*sc};
    } else {
        union { bf16 h[8]; uint4 u; } o;
#pragma unroll
        for (int c = 0; c < 8; ++c) o.h[c] = __float2bfloat16((a0[c] + a1[c]) * sc);
        *(uint4*)((ushort*)Gdst + (size_t)v * 512 + col0 + sl * 8) = o.u;
    }
}

// ---------------- full-width MFMA GEMM: A[N,KK] @ Bt[CC][KK]^T (+bias,+G3,act) ----------------
// One block = 128 rows x CC cols (no column split -> A streamed once). 4 waves 2x2;
// wave tile 64 rows x CC/2 cols = 4 x NT MFMA tiles, NT = CC/32.
// ACT: 0 raw bf16; 1 relu bf16; 2 sigmoid(acc + bias + G3) fp32.
template<int CC, int KK, int ACT>
__global__ __launch_bounds__(256) void k_gemm_w(const ushort* __restrict__ A, int AST,
                                                const bf16* __restrict__ Bt,
                                                const float* __restrict__ bias,
                                                const float* __restrict__ G3,
                                                void* __restrict__ Out, int OST, int OOFF) {
    __shared__ bf16 As[128 * 32];   // 8 KB
    __shared__ bf16 Bs[CC * 32];    // 16 KB (CC=256) / 8 KB (CC=128)
    const int NT = CC / 32;
    int t = threadIdx.x;
    int wave = t >> 6, lane = t & 63;
    int r0 = blockIdx.x * 128;
    int wr = wave >> 1, wc = wave & 1;

    f4v acc[4][NT];
#pragma unroll
    for (int i = 0; i < 4; ++i)
#pragma unroll
        for (int j = 0; j < NT; ++j) acc[i][j] = (f4v){0.f, 0.f, 0.f, 0.f};

    const char* Ab = (const char*)A;
    const char* Bb = (const char*)Bt;
    for (int k0 = 0; k0 < KK; k0 += 32) {
#pragma unroll
        for (int r = 0; r < 2; ++r) {                   // A: 8 KB
            int o = r * 4096 + wave * 1024 + lane * 16;
            int row = o >> 6, kb = o & 63;
            if (r0 + row < NNODES)
                gld_lds16(Ab + ((size_t)(r0 + row) * AST + k0) * 2 + kb, (char*)As + o);
        }
#pragma unroll
        for (int r = 0; r < CC / 64; ++r) {             // B: CC*64 bytes
            int o = r * 4096 + wave * 1024 + lane * 16;
            int row = o >> 6, kb = o & 63;
            gld_lds16(Bb + ((size_t)row * KK + k0) * 2 + kb, (char*)Bs + o);
        }
        __syncthreads();
        int ml = lane & 15, kq = (lane >> 4) * 8;
        s8v a[4], b[NT];
#pragma unroll
        for (int i = 0; i < 4; ++i)
            a[i] = *(const s8v*)&As[(wr * 64 + i * 16 + ml) * 32 + kq];
#pragma unroll
        for (int j = 0; j < NT; ++j)
            b[j] = *(const s8v*)&Bs[(wc * (CC / 2) + j * 16 + ml) * 32 + kq];
#pragma unroll
        for (int i = 0; i < 4; ++i)
#pragma unroll
            for (int j = 0; j < NT; ++j)
                acc[i][j] = __builtin_amdgcn_mfma_f32_16x16x32_bf16(a[i], b[j], acc[i][j], 0, 0, 0);
        __syncthreads();
    }
    // epilogue: C/D layout col=lane&15, row=(lane>>4)*4+reg
    int ml = lane & 15, q4 = (lane >> 4) * 4;
#pragma unroll
    for (int i = 0; i < 4; ++i) {
#pragma unroll
        for (int rr = 0; rr < 4; ++rr) {
            int grow = r0 + wr * 64 + i * 16 + q4 + rr;
            if (grow < NNODES) {
#pragma unroll
                for (int j = 0; j < NT; ++j) {
                    int gcol = wc * (CC / 2) + j * 16 + ml;
                    float vv = acc[i][j][rr];
                    if (ACT == 0) {
                        ((ushort*)Out)[(size_t)grow * OST + OOFF + gcol] =
                            __bfloat16_as_ushort(__float2bfloat16(vv));
                    } else if (ACT == 1) {
                        vv += bias[gcol];
                        ((ushort*)Out)[(size_t)grow * OST + OOFF + gcol] =
                            __bfloat16_as_ushort(__float2bfloat16(fmaxf(vv, 0.f)));
                    } else {
                        vv += bias[gcol] + G3[(size_t)grow * 128 + gcol];
                        ((float*)Out)[(size_t)grow * OST + gcol] = 1.f / (1.f + expf(-vv));
                    }
                }
            }
        }
    }
}

// ---------------- launcher ----------------

extern "C" void kernel_launch(void* const* d_in, const int* in_sizes, int n_in,
                              void* d_out, int out_size, void* d_ws, size_t ws_size,
                              hipStream_t stream) {
    const float* x   = (const float*)d_in[0];
    const int*   ei  = (const int*)d_in[1];
    const float* w1  = (const float*)d_in[3];
    const float* lw1 = (const float*)d_in[4];
    const float* lb1 = (const float*)d_in[5];
    const float* w2  = (const float*)d_in[6];
    const float* lw2 = (const float*)d_in[7];
    const float* lb2 = (const float*)d_in[8];
    const float* w3  = (const float*)d_in[9];
    const float* lw3 = (const float*)d_in[10];
    const float* lb3 = (const float*)d_in[11];
    float* out = (float*)d_out;

    char* ws = (char*)d_ws;
    size_t off = 0;
    auto alloc = [&](size_t bytes) -> void* {
        void* p = ws + off;
        off += (bytes + 255) & ~(size_t)255;
        return p;
    };
    int*    in_cnt     = (int*)alloc((size_t)HBINS * 4);
    float*  rsqrt_out  = (float*)alloc((size_t)HBINS * 4);
    int*    offsets    = (int*)alloc((size_t)(NNODES + 1) * 4);
    int*    cursor     = (int*)alloc((size_t)NNODES * 4);
    int*    block_sums = (int*)alloc((size_t)256 * 4);
    int*    block_base = (int*)alloc((size_t)256 * 4);
    ushort* partials   = (ushort*)alloc((size_t)2 * HNB * HBINS * 2);   // 25.7 MB
    int2*   edge_sw    = (int2*)alloc((size_t)NEDGES * 8);              // 6.4 MB
    bf16*   wt1        = (bf16*)alloc((size_t)256 * 512 * 2);
    bf16*   wt2        = (bf16*)alloc((size_t)256 * 512 * 2);
    bf16*   wt3a       = (bf16*)alloc((size_t)128 * 256 * 2);
    bf16*   wt3b       = (bf16*)alloc((size_t)128 * 256 * 2);
    ushort* ghA        = (ushort*)alloc((size_t)NNODES * 512 * 2);      // 51.2 MB
    ushort* ghB        = (ushort*)alloc((size_t)NNODES * 512 * 2);      // 51.2 MB
    ushort* xw3        = (ushort*)alloc((size_t)NNODES * 128 * 2);      // 12.8 MB
    float*  G3         = (float*)alloc((size_t)NNODES * 128 * 4);       // 25.6 MB

    // weights
    k_packbt<<<512, 256, 0, stream>>>(w1, lw1, wt1, 256);
    k_packbt<<<512, 256, 0, stream>>>(w2, lw2, wt2, 256);
    k_packt<<<128, 256, 0, stream>>>(w3, wt3a);
    k_packt<<<128, 256, 0, stream>>>(lw3, wt3b);
    // x -> bf16 into ghA right half
    k_f2b_strided<<<(NNODES * 64 + 255) / 256, 256, 0, stream>>>(x, ghA);

    // graph preprocessing
    k_hist<<<dim3(HNB, 2), 256, 0, stream>>>(ei, partials);
    k_hist_reduce<<<dim3(SCAN_NB, 2), 256, 0, stream>>>(partials, rsqrt_out, in_cnt, block_sums);
    k_scan_blocks<<<1, 256, 0, stream>>>(block_sums, block_base, SCAN_NB);
    k_scan_final<<<SCAN_NB, 256, 0, stream>>>(in_cnt, block_base, offsets, cursor);
    k_scatter<<<(NEDGES + 255) / 256, 256, 0, stream>>>(ei, rsqrt_out, cursor, edge_sw);

    dim3 g4((NNODES + 31) / 32, 4);   // gather, 4 column passes (256 cols)
    dim3 g2((NNODES + 31) / 32, 2);   // gather, 2 column passes (128 cols)
    int gx = (NNODES + 127) / 128;    // 391

    // layer 1: G1 = S.xb -> ghA left; h1 = relu([G1|xb]@wt1 + b1) -> ghB right
    k_gather<512, 0><<<g4, 256, 0, stream>>>(ghA + 256, offsets, edge_sw, ghA);
    k_gemm_w<256, 512, 1><<<gx, 256, 0, stream>>>(ghA, 512, wt1, lb1, nullptr, ghB, 512, 256);
    // layer 2: G2 = S.h1 -> ghB left; h2 -> ghA right
    k_gather<512, 0><<<g4, 256, 0, stream>>>(ghB + 256, offsets, edge_sw, ghB);
    k_gemm_w<256, 512, 1><<<gx, 256, 0, stream>>>(ghB, 512, wt2, lb2, nullptr, ghA, 512, 256);
    // layer 3: xw3 = h2@w3 (128 cols); G3 = in_norm*(S.xw3) fp32; out = sigmoid(G3 + h2@lw3 + b3)
    k_gemm_w<128, 256, 0><<<gx, 256, 0, stream>>>(ghA + 256, 512, wt3a, nullptr, nullptr, xw3, 128, 0);
    k_gather<128, 1><<<g2, 256, 0, stream>>>(xw3, offsets, edge_sw, G3);
    k_gemm_w<128, 256, 2><<<gx, 256, 0, stream>>>(ghA + 256, 512, wt3b, lb3, G3, out, 128, 0);
}